// Round 2
// baseline (1465.818 us; speedup 1.0000x reference)
//
#include <hip/hip_runtime.h>
#include <hip/hip_bf16.h>

#define EPSB 1e-5f

// ---------------------------------------------------------------- sub = x1-x2
__global__ __launch_bounds__(256) void k_sub(const float* __restrict__ x1,
                                             const float* __restrict__ x2,
                                             float* __restrict__ sub) {
  int i = blockIdx.x * 256 + threadIdx.x;   // total 4*256*4096 = 4194304
  sub[i] = x1[i] - x2[i];
}

// ------------------------------------------- grouped 3x3 conv (2 in ch/group)
// concat channel c<256 -> sub[c], c>=256 -> xs[c-256]
// out h[b][o<512][4096], o uses input channels {o&~1, (o&~1)+1}
__global__ __launch_bounds__(256) void k_dwconv(const float* __restrict__ sub,
                                                const float* __restrict__ xs,
                                                const float* __restrict__ w,
                                                const float* __restrict__ bias,
                                                float* __restrict__ h) {
  int idx = blockIdx.x * 256 + threadIdx.x;   // 4*512*4096 = 8388608
  int pix = idx & 4095;
  int o   = (idx >> 12) & 511;
  int b   = idx >> 21;
  int y = pix >> 6, x = pix & 63;
  float wr[18];
  const float* wp = w + o * 18;
#pragma unroll
  for (int i = 0; i < 18; i++) wr[i] = wp[i];
  float acc = bias[o];
  int cbase = (o & ~1) & 255;
  bool use_sub = (o < 256);
  const float* s0 = (use_sub ? sub : xs) + ((size_t)(b * 256 + cbase) << 12);
#pragma unroll
  for (int ky = 0; ky < 3; ky++) {
    int yy = y + ky - 1;
    if (yy < 0 || yy > 63) continue;
#pragma unroll
    for (int kx = 0; kx < 3; kx++) {
      int xx = x + kx - 1;
      if (xx < 0 || xx > 63) continue;
      int off = yy * 64 + xx;
      acc += wr[ky * 3 + kx] * s0[off] + wr[9 + ky * 3 + kx] * s0[4096 + off];
    }
  }
  h[idx] = acc;
}

// --------------------------- generic 1x1-conv GEMM: Out[oc,p] = W[oc,:]@In[:,p]
// epilogue: (dot + bias)  [optionally *bn_scale + bn_shift]  [optionally relu]
// tr_out: write Out[b][p][OC] instead of Out[b][oc][4096]
// tile 128oc x 128p, BK=16, 256 threads, 8x8 per thread
__global__ __launch_bounds__(256) void k_gemm(
    const float* __restrict__ In, const float* __restrict__ W,
    const float* __restrict__ bias,
    const float* __restrict__ bng, const float* __restrict__ bnb,
    const float* __restrict__ bnm, const float* __restrict__ bnv,
    int has_bn, int relu, int tr_out,
    float* __restrict__ Out, int OC, int IC) {
  __shared__ float Wl[16 * 132];
  __shared__ float Il[16 * 132];
  int t = threadIdx.x;
  int p0 = blockIdx.x * 128;
  int oc0 = blockIdx.y * 128;
  int b = blockIdx.z;
  const float* Inb = In + (size_t)b * IC * 4096;
  int tx = t & 15, ty = t >> 4;
  float acc[8][8];
#pragma unroll
  for (int r = 0; r < 8; r++)
#pragma unroll
    for (int c = 0; c < 8; c++) acc[r][c] = 0.f;

  for (int kc = 0; kc < IC; kc += 16) {
    __syncthreads();
    {   // stage W: 128 oc x 16 k
      int i = t >> 1;
      int kb = (t & 1) * 8;
      int ocg = oc0 + i;
#pragma unroll
      for (int u = 0; u < 8; u++) {
        float val = (ocg < OC) ? W[(size_t)ocg * IC + kc + kb + u] : 0.f;
        Wl[(kb + u) * 132 + i] = val;
      }
    }
    {   // stage In: 16 k x 128 p  (float4)
      int kk = t >> 4;
      int pb = (t & 15) * 8;
      const float* src = Inb + (size_t)(kc + kk) * 4096 + p0 + pb;
      float4 v0 = *(const float4*)(src);
      float4 v1 = *(const float4*)(src + 4);
      *(float4*)&Il[kk * 132 + pb] = v0;
      *(float4*)&Il[kk * 132 + pb + 4] = v1;
    }
    __syncthreads();
#pragma unroll
    for (int kk = 0; kk < 16; kk++) {
      float4 a0 = *(const float4*)&Wl[kk * 132 + ty * 4];
      float4 a1 = *(const float4*)&Wl[kk * 132 + 64 + ty * 4];
      float4 b0 = *(const float4*)&Il[kk * 132 + tx * 4];
      float4 b1 = *(const float4*)&Il[kk * 132 + 64 + tx * 4];
      float af[8] = {a0.x, a0.y, a0.z, a0.w, a1.x, a1.y, a1.z, a1.w};
      float bf[8] = {b0.x, b0.y, b0.z, b0.w, b1.x, b1.y, b1.z, b1.w};
#pragma unroll
      for (int r = 0; r < 8; r++)
#pragma unroll
        for (int c = 0; c < 8; c++) acc[r][c] += af[r] * bf[c];
    }
  }

#pragma unroll
  for (int r = 0; r < 8; r++) {
    int ocl = (r < 4) ? (ty * 4 + r) : (64 + ty * 4 + r - 4);
    int oc = oc0 + ocl;
    if (oc >= OC) continue;
    float bs = bias[oc];
    float scale, shift;
    if (has_bn) {
      float g = bng[oc], bb = bnb[oc];
      float m = bnm[oc], v = bnv[oc];
      scale = g * rsqrtf(v + EPSB);
      shift = bs * scale + bb - m * scale;
    } else { scale = 1.f; shift = bs; }
#pragma unroll
    for (int c = 0; c < 8; c++) {
      int pl = (c < 4) ? (tx * 4 + c) : (64 + tx * 4 + c - 4);
      int p = p0 + pl;
      float val = acc[r][c] * scale + shift;
      if (relu) val = fmaxf(val, 0.f);
      if (tr_out) Out[(size_t)b * 4096 * OC + (size_t)p * OC + oc] = val;
      else        Out[(size_t)b * OC * 4096 + (size_t)oc * 4096 + p] = val;
    }
  }
}

// -------------------------------------------------- flash attention + residual
// qt,kt: [B][4096][32] fp32; v: [B][256][4096] fp32
// out[b,c,q] = gamma * (sum_k exp(q.k) * v[c,k]) / (sum_k exp(q.k)) + x1
// block: 256 thr, Tq=32 queries, Tk=32 per tile. grid (128, B)
__global__ __launch_bounds__(256) void k_attn(const float* __restrict__ qt,
                                              const float* __restrict__ kt,
                                              const float* __restrict__ v,
                                              const float* __restrict__ x1,
                                              const float* __restrict__ gamma,
                                              float* __restrict__ out) {
  __shared__ float kl[32 * 36];
  __shared__ float pl[32 * 36];
  __shared__ float vl[32 * 256];
  __shared__ float lred[32 * 17];
  __shared__ float lfin[32];
  int t = threadIdx.x;
  int q0 = blockIdx.x * 32;
  int b = blockIdx.y;

  // score-phase mapping: 2 queries (i2, i2+16), 2 k-cols per thread
  int i2 = t & 15;
  int jg = t >> 4;          // 0..15
  float4 qa[8], qb[8];
  {
    const float4* pa = (const float4*)(qt + ((size_t)b * 4096 + q0 + i2) * 32);
    const float4* pb = (const float4*)(qt + ((size_t)b * 4096 + q0 + i2 + 16) * 32);
#pragma unroll
    for (int u = 0; u < 8; u++) { qa[u] = pa[u]; qb[u] = pb[u]; }
  }
  float lpa = 0.f, lpb = 0.f;

  // PV mapping: 4 queries x 8 channels per thread
  int qg = t >> 5;          // 0..7  -> queries q0 + qg*4 + qq
  int cg = t & 31;          // channels cg*8 .. +7
  float accq[4][8];
#pragma unroll
  for (int qq = 0; qq < 4; qq++)
#pragma unroll
    for (int k = 0; k < 8; k++) accq[qq][k] = 0.f;

  const float* vb = v + ((size_t)b << 20);
  const float4* klp = (const float4*)kl;
  const float4* plp = (const float4*)pl;
  const float4* vlp = (const float4*)vl;

  for (int j0 = 0; j0 < 4096; j0 += 32) {
    __syncthreads();
    {   // stage k tile: 32j x 32d (from kt [n][32])
      int j = t >> 3, dc = (t & 7) * 4;
      float4 kv = *(const float4*)(kt + ((size_t)b * 4096 + j0 + j) * 32 + dc);
      *(float4*)&kl[j * 36 + dc] = kv;
    }
    {   // stage v tile: 32j x 256c (transpose from v [c][n])
      const float* vr = vb + ((size_t)t << 12) + j0;
#pragma unroll
      for (int j4 = 0; j4 < 8; j4++) {
        float4 vv = *(const float4*)(vr + j4 * 4);
        vl[(j4 * 4 + 0) * 256 + t] = vv.x;
        vl[(j4 * 4 + 1) * 256 + t] = vv.y;
        vl[(j4 * 4 + 2) * 256 + t] = vv.z;
        vl[(j4 * 4 + 3) * 256 + t] = vv.w;
      }
    }
    __syncthreads();
    // scores + exp (logits tiny: skip max-subtraction; clamp for inf-safety)
#pragma unroll
    for (int jj = 0; jj < 2; jj++) {
      int j = (jg << 1) + jj;
      float sa = 0.f, sb = 0.f;
#pragma unroll
      for (int u = 0; u < 8; u++) {
        float4 kv = klp[j * 9 + u];
        sa += qa[u].x * kv.x + qa[u].y * kv.y + qa[u].z * kv.z + qa[u].w * kv.w;
        sb += qb[u].x * kv.x + qb[u].y * kv.y + qb[u].z * kv.z + qb[u].w * kv.w;
      }
      float pa = __expf(fminf(sa, 80.f));
      float pb = __expf(fminf(sb, 80.f));
      pl[j * 36 + i2] = pa;
      pl[j * 36 + i2 + 16] = pb;
      lpa += pa; lpb += pb;
    }
    __syncthreads();
    // PV accumulate
#pragma unroll 4
    for (int j = 0; j < 32; j++) {
      float4 pv = plp[j * 9 + qg];
      float4 v0 = vlp[j * 64 + (cg << 1)];
      float4 v1 = vlp[j * 64 + (cg << 1) + 1];
      float pq[4] = {pv.x, pv.y, pv.z, pv.w};
#pragma unroll
      for (int qq = 0; qq < 4; qq++) {
        accq[qq][0] += pq[qq] * v0.x;
        accq[qq][1] += pq[qq] * v0.y;
        accq[qq][2] += pq[qq] * v0.z;
        accq[qq][3] += pq[qq] * v0.w;
        accq[qq][4] += pq[qq] * v1.x;
        accq[qq][5] += pq[qq] * v1.y;
        accq[qq][6] += pq[qq] * v1.z;
        accq[qq][7] += pq[qq] * v1.w;
      }
    }
  }

  // reduce row sums l over the 16 jg slices
  lred[i2 * 17 + jg] = lpa;
  lred[(i2 + 16) * 17 + jg] = lpb;
  __syncthreads();
  if (t < 32) {
    float s = 0.f;
#pragma unroll
    for (int u = 0; u < 16; u++) s += lred[t * 17 + u];
    lfin[t] = 1.f / s;
  }
  __syncthreads();

  float gm = gamma[0];
#pragma unroll
  for (int qq = 0; qq < 4; qq++) {
    int qi = qg * 4 + qq;
    float linv = lfin[qi];
    int pix = q0 + qi;
#pragma unroll
    for (int k = 0; k < 8; k++) {
      int c = cg * 8 + k;
      size_t gidx = (((size_t)b * 256 + c) << 12) + pix;
      out[gidx] = gm * accq[qq][k] * linv + x1[gidx];
    }
  }
}

// ------------------------------------------------------------------- launcher
extern "C" void kernel_launch(void* const* d_in, const int* in_sizes, int n_in,
                              void* d_out, int out_size, void* d_ws, size_t ws_size,
                              hipStream_t stream) {
  const float* x1    = (const float*)d_in[0];
  const float* x2    = (const float*)d_in[1];
  const float* w1_dw = (const float*)d_in[2];
  const float* b1_dw = (const float*)d_in[3];
  const float* w1_pw = (const float*)d_in[4];
  const float* b1_pw = (const float*)d_in[5];
  const float* bn1_g = (const float*)d_in[6];
  const float* bn1_b = (const float*)d_in[7];
  const float* bn1_m = (const float*)d_in[8];
  const float* bn1_v = (const float*)d_in[9];
  const float* w2_dw = (const float*)d_in[10];
  const float* b2_dw = (const float*)d_in[11];
  const float* w2_pw = (const float*)d_in[12];
  const float* b2_pw = (const float*)d_in[13];
  const float* bn2_g = (const float*)d_in[14];
  const float* bn2_b = (const float*)d_in[15];
  const float* bn2_m = (const float*)d_in[16];
  const float* bn2_v = (const float*)d_in[17];
  const float* wq    = (const float*)d_in[18];
  const float* bq    = (const float*)d_in[19];
  const float* wk    = (const float*)d_in[20];
  const float* bk    = (const float*)d_in[21];
  const float* wv    = (const float*)d_in[22];
  const float* bv    = (const float*)d_in[23];
  const float* gamma = (const float*)d_in[24];

  // workspace aliasing (all offsets in floats; kernels serialize on stream):
  //   sub [0, 4M)          live: k_sub .. dw2
  //   h   [4M, 12M)        live: dw1..pw1, dw2..pw2 (reused)
  //   x3  [12M, 16M)       live: pw1 .. k/v convs
  //   x4  [0, 4M)          overwrites dead sub (pw2 onward)
  //   qt  [4M, 4.5M)       overwrites dead h
  //   kt  [4.5M, 5M)
  //   vv  [5M, 9M)
  // peak footprint: 16M floats = 64 MB
  float* ws  = (float*)d_ws;
  float* sub = ws;
  float* h   = ws + 4194304;
  float* x3  = ws + 12582912;
  float* x4  = ws;
  float* qt  = ws + 4194304;
  float* kt  = ws + 4718592;
  float* vv  = ws + 5242880;

  k_sub<<<16384, 256, 0, stream>>>(x1, x2, sub);

  // block 1: concat(sub, x1) -> dwconv -> pw+bn+relu -> x3
  k_dwconv<<<32768, 256, 0, stream>>>(sub, x1, w1_dw, b1_dw, h);
  k_gemm<<<dim3(32, 2, 4), 256, 0, stream>>>(h, w1_pw, b1_pw, bn1_g, bn1_b,
                                             bn1_m, bn1_v, 1, 1, 0, x3, 256, 512);
  // block 2: concat(sub, x2) -> dwconv -> pw+bn+relu -> x4
  k_dwconv<<<32768, 256, 0, stream>>>(sub, x2, w2_dw, b2_dw, h);
  k_gemm<<<dim3(32, 2, 4), 256, 0, stream>>>(h, w2_pw, b2_pw, bn2_g, bn2_b,
                                             bn2_m, bn2_v, 1, 1, 0, x4, 256, 512);
  // q from x4, k from x3 (both transposed [n][32]), v from x3
  k_gemm<<<dim3(32, 1, 4), 256, 0, stream>>>(x4, wq, bq, nullptr, nullptr,
                                             nullptr, nullptr, 0, 0, 1, qt, 32, 256);
  k_gemm<<<dim3(32, 1, 4), 256, 0, stream>>>(x3, wk, bk, nullptr, nullptr,
                                             nullptr, nullptr, 0, 0, 1, kt, 32, 256);
  k_gemm<<<dim3(32, 2, 4), 256, 0, stream>>>(x3, wv, bv, nullptr, nullptr,
                                             nullptr, nullptr, 0, 0, 0, vv, 256, 256);

  k_attn<<<dim3(128, 4), 256, 0, stream>>>(qt, kt, vv, x1, gamma, (float*)d_out);
}

// Round 3
// 688.193 us; speedup vs baseline: 2.1300x; 2.1300x over previous
//
#include <hip/hip_runtime.h>
#include <hip/hip_bf16.h>

#define EPSB 1e-5f

typedef __hip_bfloat16 bf16;
typedef __attribute__((ext_vector_type(8))) short bf16x8;
typedef __attribute__((ext_vector_type(4))) float f32x4;

// ---------------------------------------------------------------- sub = x1-x2
__global__ __launch_bounds__(256) void k_sub(const float* __restrict__ x1,
                                             const float* __restrict__ x2,
                                             float* __restrict__ sub) {
  int i = blockIdx.x * 256 + threadIdx.x;
  sub[i] = x1[i] - x2[i];
}

// ------------------------------------------- grouped 3x3 conv (2 in ch/group)
__global__ __launch_bounds__(256) void k_dwconv(const float* __restrict__ sub,
                                                const float* __restrict__ xs,
                                                const float* __restrict__ w,
                                                const float* __restrict__ bias,
                                                float* __restrict__ h) {
  int idx = blockIdx.x * 256 + threadIdx.x;   // 4*512*4096
  int pix = idx & 4095;
  int o   = (idx >> 12) & 511;
  int b   = idx >> 21;
  int y = pix >> 6, x = pix & 63;
  float wr[18];
  const float* wp = w + o * 18;
#pragma unroll
  for (int i = 0; i < 18; i++) wr[i] = wp[i];
  float acc = bias[o];
  int cbase = (o & ~1) & 255;
  bool use_sub = (o < 256);
  const float* s0 = (use_sub ? sub : xs) + ((size_t)(b * 256 + cbase) << 12);
#pragma unroll
  for (int ky = 0; ky < 3; ky++) {
    int yy = y + ky - 1;
    if (yy < 0 || yy > 63) continue;
#pragma unroll
    for (int kx = 0; kx < 3; kx++) {
      int xx = x + kx - 1;
      if (xx < 0 || xx > 63) continue;
      int off = yy * 64 + xx;
      acc += wr[ky * 3 + kx] * s0[off] + wr[9 + ky * 3 + kx] * s0[4096 + off];
    }
  }
  h[idx] = acc;
}

// --------------------------- generic 1x1-conv GEMM: Out[oc,p] = W[oc,:]@In[:,p]
// tile 128oc x 128p, BK=16, 256 threads, 8x8 per thread
// out_bf16: write __hip_bfloat16 instead of float
__global__ __launch_bounds__(256) void k_gemm(
    const float* __restrict__ In, const float* __restrict__ W,
    const float* __restrict__ bias,
    const float* __restrict__ bng, const float* __restrict__ bnb,
    const float* __restrict__ bnm, const float* __restrict__ bnv,
    int has_bn, int relu, int tr_out, int out_bf16,
    void* __restrict__ OutV, int OC, int IC) {
  __shared__ float Wl[16 * 132];
  __shared__ float Il[16 * 132];
  int t = threadIdx.x;
  int p0 = blockIdx.x * 128;
  int oc0 = blockIdx.y * 128;
  int b = blockIdx.z;
  const float* Inb = In + (size_t)b * IC * 4096;
  int tx = t & 15, ty = t >> 4;
  float acc[8][8];
#pragma unroll
  for (int r = 0; r < 8; r++)
#pragma unroll
    for (int c = 0; c < 8; c++) acc[r][c] = 0.f;

  for (int kc = 0; kc < IC; kc += 16) {
    __syncthreads();
    {   // stage W: 128 oc x 16 k
      int i = t >> 1;
      int kb = (t & 1) * 8;
      int ocg = oc0 + i;
#pragma unroll
      for (int u = 0; u < 8; u++) {
        float val = (ocg < OC) ? W[(size_t)ocg * IC + kc + kb + u] : 0.f;
        Wl[(kb + u) * 132 + i] = val;
      }
    }
    {   // stage In: 16 k x 128 p
      int kk = t >> 4;
      int pb = (t & 15) * 8;
      const float* src = Inb + (size_t)(kc + kk) * 4096 + p0 + pb;
      float4 v0 = *(const float4*)(src);
      float4 v1 = *(const float4*)(src + 4);
      *(float4*)&Il[kk * 132 + pb] = v0;
      *(float4*)&Il[kk * 132 + pb + 4] = v1;
    }
    __syncthreads();
#pragma unroll
    for (int kk = 0; kk < 16; kk++) {
      float4 a0 = *(const float4*)&Wl[kk * 132 + ty * 4];
      float4 a1 = *(const float4*)&Wl[kk * 132 + 64 + ty * 4];
      float4 b0 = *(const float4*)&Il[kk * 132 + tx * 4];
      float4 b1 = *(const float4*)&Il[kk * 132 + 64 + tx * 4];
      float af[8] = {a0.x, a0.y, a0.z, a0.w, a1.x, a1.y, a1.z, a1.w};
      float bf[8] = {b0.x, b0.y, b0.z, b0.w, b1.x, b1.y, b1.z, b1.w};
#pragma unroll
      for (int r = 0; r < 8; r++)
#pragma unroll
        for (int c = 0; c < 8; c++) acc[r][c] += af[r] * bf[c];
    }
  }

#pragma unroll
  for (int r = 0; r < 8; r++) {
    int ocl = (r < 4) ? (ty * 4 + r) : (64 + ty * 4 + r - 4);
    int oc = oc0 + ocl;
    if (oc >= OC) continue;
    float bs = bias[oc];
    float scale, shift;
    if (has_bn) {
      float g = bng[oc], bb = bnb[oc];
      float m = bnm[oc], v = bnv[oc];
      scale = g * rsqrtf(v + EPSB);
      shift = bs * scale + bb - m * scale;
    } else { scale = 1.f; shift = bs; }
#pragma unroll
    for (int c = 0; c < 8; c++) {
      int pl = (c < 4) ? (tx * 4 + c) : (64 + tx * 4 + c - 4);
      int p = p0 + pl;
      float val = acc[r][c] * scale + shift;
      if (relu) val = fmaxf(val, 0.f);
      size_t idx = tr_out ? ((size_t)b * 4096 * OC + (size_t)p * OC + oc)
                          : ((size_t)b * OC * 4096 + (size_t)oc * 4096 + p);
      if (out_bf16) ((bf16*)OutV)[idx] = __float2bfloat16(val);
      else          ((float*)OutV)[idx] = val;
    }
  }
}

// ------------------------------------------- MFMA flash attention + residual
// qb,kb: [B][4096][32] bf16 ; vb: [B][256][4096] bf16 ; out fp32
// wg: 64-query tile, 256 thr (4 waves). k-tiles of 64. grid (64, B).
// mfma_f32_16x16x32_bf16; A: m=lane&15,k=quad*8+j ; C/D: col=lane&15,row=quad*4+reg
__global__ __launch_bounds__(256) void k_attn_mfma(
    const bf16* __restrict__ qb, const bf16* __restrict__ kb,
    const bf16* __restrict__ vb, const float* __restrict__ x1,
    const float* __restrict__ gamma, float* __restrict__ out) {
  __shared__ bf16 Vt[256][72];   // V^T tile, [c][k] (k contiguous), stride 72 for bank spread
  __shared__ bf16 Pl[64][72];    // P tile, [q][k]
  __shared__ float lsum[64];

  int t = threadIdx.x;
  int w = t >> 6, lane = t & 63;
  int l16 = lane & 15, quad = lane >> 4;
  int q0 = blockIdx.x * 64;
  int b = blockIdx.y;

  const bf16* kbb = kb + (size_t)b * 4096 * 32;
  const bf16* vbb = vb + (size_t)b * 256 * 4096;

  // Q A-fragment, held in registers the whole loop (d=32 = one K=32 fragment)
  bf16x8 qfrag = *(const bf16x8*)(qb + ((size_t)(b * 4096 + q0 + w * 16 + l16) * 32) + quad * 8);

  f32x4 acc[4][4];
#pragma unroll
  for (int mi = 0; mi < 4; mi++)
#pragma unroll
    for (int nj = 0; nj < 4; nj++) acc[mi][nj] = (f32x4){0.f, 0.f, 0.f, 0.f};
  float lpart[4] = {0.f, 0.f, 0.f, 0.f};

  int sc = t >> 3;   // Vt staging: c base (0..31)
  int skp = t & 7;   // Vt staging: 16B chunk within 64-k row

  for (int j0 = 0; j0 < 4096; j0 += 64) {
    __syncthreads();
    // stage V^T tile: 64 k x 256 c (bf16x8 global loads, 128B-contiguous per 8 lanes)
#pragma unroll
    for (int u = 0; u < 8; u++) {
      int c = sc + u * 32;
      bf16x8 vv = *(const bf16x8*)(vbb + (size_t)c * 4096 + j0 + skp * 8);
      *(bf16x8*)(&Vt[c][skp * 8]) = vv;
    }
    // S-phase: wave w computes rows w*16..+15 x all 64 keys (K frags from global/L2)
#pragma unroll
    for (int ni = 0; ni < 4; ni++) {
      bf16x8 kfrag = *(const bf16x8*)(kbb + (size_t)(j0 + ni * 16 + l16) * 32 + quad * 8);
      f32x4 s = __builtin_amdgcn_mfma_f32_16x16x32_bf16(
          qfrag, kfrag, (f32x4){0.f, 0.f, 0.f, 0.f}, 0, 0, 0);
#pragma unroll
      for (int r = 0; r < 4; r++) {
        float p = __expf(fminf(s[r], 80.f));   // logits tiny; clamp for safety
        lpart[r] += p;
        Pl[w * 16 + quad * 4 + r][ni * 16 + l16] = __float2bfloat16(p);
      }
    }
    __syncthreads();
    // PV: wave w owns c-range w*64..+63 (4 n-tiles) x 4 m-tiles, K=64 in 2 chunks
#pragma unroll
    for (int kc = 0; kc < 2; kc++) {
      bf16x8 af[4], bfr[4];
#pragma unroll
      for (int mi = 0; mi < 4; mi++)
        af[mi] = *(const bf16x8*)(&Pl[mi * 16 + l16][kc * 32 + quad * 8]);
#pragma unroll
      for (int nj = 0; nj < 4; nj++)
        bfr[nj] = *(const bf16x8*)(&Vt[w * 64 + nj * 16 + l16][kc * 32 + quad * 8]);
#pragma unroll
      for (int mi = 0; mi < 4; mi++)
#pragma unroll
        for (int nj = 0; nj < 4; nj++)
          acc[mi][nj] = __builtin_amdgcn_mfma_f32_16x16x32_bf16(
              af[mi], bfr[nj], acc[mi][nj], 0, 0, 0);
    }
  }

  // softmax denominators: reduce lpart over the 16 col-lanes (l16 bits only)
#pragma unroll
  for (int r = 0; r < 4; r++) {
    float v = lpart[r];
    v += __shfl_xor(v, 1);
    v += __shfl_xor(v, 2);
    v += __shfl_xor(v, 4);
    v += __shfl_xor(v, 8);
    lpart[r] = v;
  }
  if (l16 == 0) {
#pragma unroll
    for (int r = 0; r < 4; r++) lsum[w * 16 + quad * 4 + r] = lpart[r];
  }
  __syncthreads();

  float gm = gamma[0];
#pragma unroll
  for (int mi = 0; mi < 4; mi++) {
    f32x4 lv = *(const f32x4*)&lsum[mi * 16 + quad * 4];
    float li0 = 1.f / lv[0], li1 = 1.f / lv[1], li2 = 1.f / lv[2], li3 = 1.f / lv[3];
#pragma unroll
    for (int nj = 0; nj < 4; nj++) {
      int c = w * 64 + nj * 16 + l16;
      size_t base = (((size_t)(b * 256 + c)) << 12) + q0 + mi * 16 + quad * 4;
      float4 xv = *(const float4*)(x1 + base);
      float4 o;
      o.x = gm * acc[mi][nj][0] * li0 + xv.x;
      o.y = gm * acc[mi][nj][1] * li1 + xv.y;
      o.z = gm * acc[mi][nj][2] * li2 + xv.z;
      o.w = gm * acc[mi][nj][3] * li3 + xv.w;
      *(float4*)(out + base) = o;
    }
  }
}

// ------------------------------------------------------------------- launcher
extern "C" void kernel_launch(void* const* d_in, const int* in_sizes, int n_in,
                              void* d_out, int out_size, void* d_ws, size_t ws_size,
                              hipStream_t stream) {
  const float* x1    = (const float*)d_in[0];
  const float* x2    = (const float*)d_in[1];
  const float* w1_dw = (const float*)d_in[2];
  const float* b1_dw = (const float*)d_in[3];
  const float* w1_pw = (const float*)d_in[4];
  const float* b1_pw = (const float*)d_in[5];
  const float* bn1_g = (const float*)d_in[6];
  const float* bn1_b = (const float*)d_in[7];
  const float* bn1_m = (const float*)d_in[8];
  const float* bn1_v = (const float*)d_in[9];
  const float* w2_dw = (const float*)d_in[10];
  const float* b2_dw = (const float*)d_in[11];
  const float* w2_pw = (const float*)d_in[12];
  const float* b2_pw = (const float*)d_in[13];
  const float* bn2_g = (const float*)d_in[14];
  const float* bn2_b = (const float*)d_in[15];
  const float* bn2_m = (const float*)d_in[16];
  const float* bn2_v = (const float*)d_in[17];
  const float* wq    = (const float*)d_in[18];
  const float* bq    = (const float*)d_in[19];
  const float* wk    = (const float*)d_in[20];
  const float* bk    = (const float*)d_in[21];
  const float* wv    = (const float*)d_in[22];
  const float* bv    = (const float*)d_in[23];
  const float* gamma = (const float*)d_in[24];

  // ws layout (float offsets):
  //   sub [0,4M)   live k_sub..dw2      x4 [0,4M)  overwrites dead sub
  //   h   [4M,12M) live dw..pw          qb/kb/vvb (bf16) overwrite dead h
  //   x3  [12M,16M) live pw1..k/v gemms
  float* ws  = (float*)d_ws;
  float* sub = ws;
  float* h   = ws + 4194304;
  float* x3  = ws + 12582912;
  float* x4  = ws;
  bf16* qb  = (bf16*)(ws + 4194304);
  bf16* kbf = qb + 524288;
  bf16* vvb = kbf + 524288;

  k_sub<<<16384, 256, 0, stream>>>(x1, x2, sub);

  k_dwconv<<<32768, 256, 0, stream>>>(sub, x1, w1_dw, b1_dw, h);
  k_gemm<<<dim3(32, 2, 4), 256, 0, stream>>>(h, w1_pw, b1_pw, bn1_g, bn1_b,
                                             bn1_m, bn1_v, 1, 1, 0, 0, x3, 256, 512);
  k_dwconv<<<32768, 256, 0, stream>>>(sub, x2, w2_dw, b2_dw, h);
  k_gemm<<<dim3(32, 2, 4), 256, 0, stream>>>(h, w2_pw, b2_pw, bn2_g, bn2_b,
                                             bn2_m, bn2_v, 1, 1, 0, 0, x4, 256, 512);

  // q from x4, k from x3 (both [n][32] bf16), v from x3 ([c][n] bf16)
  k_gemm<<<dim3(32, 1, 4), 256, 0, stream>>>(x4, wq, bq, nullptr, nullptr,
                                             nullptr, nullptr, 0, 0, 1, 1, qb, 32, 256);
  k_gemm<<<dim3(32, 1, 4), 256, 0, stream>>>(x3, wk, bk, nullptr, nullptr,
                                             nullptr, nullptr, 0, 0, 1, 1, kbf, 32, 256);
  k_gemm<<<dim3(32, 2, 4), 256, 0, stream>>>(x3, wv, bv, nullptr, nullptr,
                                             nullptr, nullptr, 0, 0, 0, 1, vvb, 256, 256);

  k_attn_mfma<<<dim3(64, 4), 256, 0, stream>>>(qb, kbf, vvb, x1, gamma, (float*)d_out);
}

// Round 4
// 394.561 us; speedup vs baseline: 3.7151x; 1.7442x over previous
//
#include <hip/hip_runtime.h>
#include <hip/hip_bf16.h>

#define EPSB 1e-5f

typedef __hip_bfloat16 bf16;
typedef __attribute__((ext_vector_type(8))) short bf16x8;
typedef __attribute__((ext_vector_type(4))) float f32x4;

__device__ __forceinline__ unsigned short f2bu(float x) {
  bf16 h = __float2bfloat16(x);
  return *reinterpret_cast<unsigned short*>(&h);
}
__device__ __forceinline__ unsigned int pk2(float lo, float hi) {
  return ((unsigned int)f2bu(hi) << 16) | (unsigned int)f2bu(lo);
}

// ---------------------------------------------------------------- sub = x1-x2
__global__ __launch_bounds__(256) void k_sub(const float* __restrict__ x1,
                                             const float* __restrict__ x2,
                                             float* __restrict__ sub) {
  int i = blockIdx.x * 256 + threadIdx.x;
  sub[i] = x1[i] - x2[i];
}

// ------------------------------------------- grouped 3x3 conv (2 in ch/group)
__global__ __launch_bounds__(256) void k_dwconv(const float* __restrict__ sub,
                                                const float* __restrict__ xs,
                                                const float* __restrict__ w,
                                                const float* __restrict__ bias,
                                                float* __restrict__ h) {
  int idx = blockIdx.x * 256 + threadIdx.x;   // 4*512*4096
  int pix = idx & 4095;
  int o   = (idx >> 12) & 511;
  int b   = idx >> 21;
  int y = pix >> 6, x = pix & 63;
  float wr[18];
  const float* wp = w + o * 18;
#pragma unroll
  for (int i = 0; i < 18; i++) wr[i] = wp[i];
  float acc = bias[o];
  int cbase = (o & ~1) & 255;
  bool use_sub = (o < 256);
  const float* s0 = (use_sub ? sub : xs) + ((size_t)(b * 256 + cbase) << 12);
#pragma unroll
  for (int ky = 0; ky < 3; ky++) {
    int yy = y + ky - 1;
    if (yy < 0 || yy > 63) continue;
#pragma unroll
    for (int kx = 0; kx < 3; kx++) {
      int xx = x + kx - 1;
      if (xx < 0 || xx > 63) continue;
      int off = yy * 64 + xx;
      acc += wr[ky * 3 + kx] * s0[off] + wr[9 + ky * 3 + kx] * s0[4096 + off];
    }
  }
  h[idx] = acc;
}

// --------------------- MFMA 1x1-conv GEMM (OC=256): Out[oc,p] = W[oc,:]@In[:,p]
// tile 128oc x 64p, BK=32, 256 thr (4 waves, 2x2). fp32 in, bf16 MFMA, fp32 acc.
// mfma_f32_16x16x32_bf16; A: m=l16,k=quad*8+j ; D: m=quad*4+reg, n=l16
__global__ __launch_bounds__(256) void k_gemm_mfma(
    const float* __restrict__ In, const float* __restrict__ W,
    const float* __restrict__ bias,
    const float* __restrict__ bng, const float* __restrict__ bnb,
    const float* __restrict__ bnm, const float* __restrict__ bnv,
    int has_bn, int relu, int out_bf16,
    void* __restrict__ OutV, int IC) {
  __shared__ __align__(16) bf16 Al[128][40];   // [oc][k], pad 40 (80B rows)
  __shared__ __align__(16) bf16 Bl[64][40];    // [p][k]

  int t = threadIdx.x;
  int w = t >> 6, lane = t & 63, l16 = lane & 15, quad = lane >> 4;
  int wr = w >> 1, wc = w & 1;          // wave = 64oc x 32p
  int p0 = blockIdx.x * 64;
  int oc0 = blockIdx.y * 128;
  int b = blockIdx.z;
  const float* Inb = In + (size_t)b * IC * 4096;

  f32x4 acc[4][2];
#pragma unroll
  for (int mi = 0; mi < 4; mi++)
#pragma unroll
    for (int nj = 0; nj < 2; nj++) acc[mi][nj] = (f32x4){0.f, 0.f, 0.f, 0.f};

  int sl = t & 15, srp = t >> 4;        // B stage: lane-in-row, k-pair
  int ocl = t >> 1, kb = (t & 1) * 16;  // A stage

  for (int kc = 0; kc < IC; kc += 32) {
    __syncthreads();
    {   // stage A: 128oc x 32k, convert fp32->bf16, [oc][k] contiguous
      const float* src = W + (size_t)(oc0 + ocl) * IC + kc + kb;
      float4 f0 = *(const float4*)(src);
      float4 f1 = *(const float4*)(src + 4);
      float4 f2 = *(const float4*)(src + 8);
      float4 f3 = *(const float4*)(src + 12);
      uint4 u0 = {pk2(f0.x, f0.y), pk2(f0.z, f0.w), pk2(f1.x, f1.y), pk2(f1.z, f1.w)};
      uint4 u1 = {pk2(f2.x, f2.y), pk2(f2.z, f2.w), pk2(f3.x, f3.y), pk2(f3.z, f3.w)};
      *(uint4*)&Al[ocl][kb] = u0;
      *(uint4*)&Al[ocl][kb + 8] = u1;
    }
    {   // stage B: 32k x 64p, transpose to [p][k] at k-pair (4B) granularity
      const float* re = Inb + (size_t)(kc + 2 * srp) * 4096 + p0 + sl;
      const float* ro = re + 4096;
#pragma unroll
      for (int j = 0; j < 4; j++) {
        float e = re[j * 16];
        float o = ro[j * 16];
        *(unsigned int*)&Bl[j * 16 + sl][2 * srp] = pk2(e, o);
      }
    }
    __syncthreads();
    bf16x8 af[4], bv[2];
#pragma unroll
    for (int mi = 0; mi < 4; mi++)
      af[mi] = *(const bf16x8*)&Al[wr * 64 + mi * 16 + l16][quad * 8];
#pragma unroll
    for (int nj = 0; nj < 2; nj++)
      bv[nj] = *(const bf16x8*)&Bl[wc * 32 + nj * 16 + l16][quad * 8];
#pragma unroll
    for (int mi = 0; mi < 4; mi++)
#pragma unroll
      for (int nj = 0; nj < 2; nj++)
        acc[mi][nj] = __builtin_amdgcn_mfma_f32_16x16x32_bf16(
            af[mi], bv[nj], acc[mi][nj], 0, 0, 0);
  }

  // epilogue: per lane 4 consecutive oc (quad*4+r) x 1 p per (mi,nj)
#pragma unroll
  for (int mi = 0; mi < 4; mi++) {
    int ocb = oc0 + wr * 64 + mi * 16 + quad * 4;
    float4 bs4 = *(const float4*)&bias[ocb];
    float4 sc4 = {1.f, 1.f, 1.f, 1.f}, sh4 = bs4;
    if (has_bn) {
      float4 g4 = *(const float4*)&bng[ocb];
      float4 b4 = *(const float4*)&bnb[ocb];
      float4 m4 = *(const float4*)&bnm[ocb];
      float4 v4 = *(const float4*)&bnv[ocb];
      sc4.x = g4.x * rsqrtf(v4.x + EPSB); sh4.x = bs4.x * sc4.x + b4.x - m4.x * sc4.x;
      sc4.y = g4.y * rsqrtf(v4.y + EPSB); sh4.y = bs4.y * sc4.y + b4.y - m4.y * sc4.y;
      sc4.z = g4.z * rsqrtf(v4.z + EPSB); sh4.z = bs4.z * sc4.z + b4.z - m4.z * sc4.z;
      sc4.w = g4.w * rsqrtf(v4.w + EPSB); sh4.w = bs4.w * sc4.w + b4.w - m4.w * sc4.w;
    }
    float sc[4] = {sc4.x, sc4.y, sc4.z, sc4.w};
    float sh[4] = {sh4.x, sh4.y, sh4.z, sh4.w};
#pragma unroll
    for (int nj = 0; nj < 2; nj++) {
      int p = p0 + wc * 32 + nj * 16 + l16;
#pragma unroll
      for (int r = 0; r < 4; r++) {
        float val = acc[mi][nj][r] * sc[r] + sh[r];
        if (relu) val = fmaxf(val, 0.f);
        size_t gi = (((size_t)(b * 256 + ocb + r)) << 12) + p;
        if (out_bf16) ((bf16*)OutV)[gi] = __float2bfloat16(val);
        else          ((float*)OutV)[gi] = val;
      }
    }
  }
}

// ---------------- MFMA q/k GEMM (OC=32, IC=256), q & k fused via blockIdx.y
// tile 32oc x 128p, out transposed [b][p][32] bf16
__global__ __launch_bounds__(256) void k_gemm_qk(
    const float* __restrict__ x4, const float* __restrict__ x3,
    const float* __restrict__ wq, const float* __restrict__ wk,
    const float* __restrict__ bq, const float* __restrict__ bk,
    bf16* __restrict__ qb, bf16* __restrict__ kb) {
  __shared__ __align__(16) bf16 Al[32][40];
  __shared__ __align__(16) bf16 Bl[128][40];

  int t = threadIdx.x;
  int w = t >> 6, lane = t & 63, l16 = lane & 15, quad = lane >> 4;
  int p0 = blockIdx.x * 128;
  int b = blockIdx.z;
  const float* In = (blockIdx.y == 0) ? x4 : x3;
  const float* W  = (blockIdx.y == 0) ? wq : wk;
  const float* bi = (blockIdx.y == 0) ? bq : bk;
  bf16* Out       = (blockIdx.y == 0) ? qb : kb;
  const float* Inb = In + (size_t)b * 256 * 4096;

  f32x4 acc[2][2];
#pragma unroll
  for (int mi = 0; mi < 2; mi++)
#pragma unroll
    for (int nj = 0; nj < 2; nj++) acc[mi][nj] = (f32x4){0.f, 0.f, 0.f, 0.f};

  int aocl = t >> 3, akb = (t & 7) * 4;
  int sl = t & 15, srp = t >> 4;

  for (int kc = 0; kc < 256; kc += 32) {
    __syncthreads();
    {   // stage A: 32oc x 32k
      const float* src = W + (size_t)aocl * 256 + kc + akb;
      float4 f0 = *(const float4*)(src);
      uint2 u = {pk2(f0.x, f0.y), pk2(f0.z, f0.w)};
      *(uint2*)&Al[aocl][akb] = u;
    }
    {   // stage B: 32k x 128p transpose
      const float* re = Inb + (size_t)(kc + 2 * srp) * 4096 + p0 + sl;
      const float* ro = re + 4096;
#pragma unroll
      for (int j = 0; j < 8; j++) {
        float e = re[j * 16];
        float o = ro[j * 16];
        *(unsigned int*)&Bl[j * 16 + sl][2 * srp] = pk2(e, o);
      }
    }
    __syncthreads();
    bf16x8 af[2], bv[2];
#pragma unroll
    for (int mi = 0; mi < 2; mi++)
      af[mi] = *(const bf16x8*)&Al[mi * 16 + l16][quad * 8];
#pragma unroll
    for (int nj = 0; nj < 2; nj++)
      bv[nj] = *(const bf16x8*)&Bl[w * 32 + nj * 16 + l16][quad * 8];
#pragma unroll
    for (int mi = 0; mi < 2; mi++)
#pragma unroll
      for (int nj = 0; nj < 2; nj++)
        acc[mi][nj] = __builtin_amdgcn_mfma_f32_16x16x32_bf16(
            af[mi], bv[nj], acc[mi][nj], 0, 0, 0);
  }

#pragma unroll
  for (int mi = 0; mi < 2; mi++) {
    int ocb = mi * 16 + quad * 4;
    float4 bs4 = *(const float4*)&bi[ocb];
    float bs[4] = {bs4.x, bs4.y, bs4.z, bs4.w};
#pragma unroll
    for (int nj = 0; nj < 2; nj++) {
      int p = p0 + w * 32 + nj * 16 + l16;
      float v0 = acc[mi][nj][0] + bs[0];
      float v1 = acc[mi][nj][1] + bs[1];
      float v2 = acc[mi][nj][2] + bs[2];
      float v3 = acc[mi][nj][3] + bs[3];
      uint2 u = {pk2(v0, v1), pk2(v2, v3)};
      *(uint2*)&Out[((size_t)(b * 4096) + p) * 32 + ocb] = u;
    }
  }
}

// ------------------------------------------- MFMA flash attention + residual
__global__ __launch_bounds__(256) void k_attn_mfma(
    const bf16* __restrict__ qb, const bf16* __restrict__ kb,
    const bf16* __restrict__ vb, const float* __restrict__ x1,
    const float* __restrict__ gamma, float* __restrict__ out) {
  __shared__ bf16 Vt[256][72];
  __shared__ bf16 Pl[64][72];
  __shared__ float lsum[64];

  int t = threadIdx.x;
  int w = t >> 6, lane = t & 63;
  int l16 = lane & 15, quad = lane >> 4;
  int q0 = blockIdx.x * 64;
  int b = blockIdx.y;

  const bf16* kbb = kb + (size_t)b * 4096 * 32;
  const bf16* vbb = vb + (size_t)b * 256 * 4096;

  bf16x8 qfrag = *(const bf16x8*)(qb + ((size_t)(b * 4096 + q0 + w * 16 + l16) * 32) + quad * 8);

  f32x4 acc[4][4];
#pragma unroll
  for (int mi = 0; mi < 4; mi++)
#pragma unroll
    for (int nj = 0; nj < 4; nj++) acc[mi][nj] = (f32x4){0.f, 0.f, 0.f, 0.f};
  float lpart[4] = {0.f, 0.f, 0.f, 0.f};

  int sc = t >> 3;
  int skp = t & 7;

  for (int j0 = 0; j0 < 4096; j0 += 64) {
    __syncthreads();
#pragma unroll
    for (int u = 0; u < 8; u++) {
      int c = sc + u * 32;
      bf16x8 vv = *(const bf16x8*)(vbb + (size_t)c * 4096 + j0 + skp * 8);
      *(bf16x8*)(&Vt[c][skp * 8]) = vv;
    }
#pragma unroll
    for (int ni = 0; ni < 4; ni++) {
      bf16x8 kfrag = *(const bf16x8*)(kbb + (size_t)(j0 + ni * 16 + l16) * 32 + quad * 8);
      f32x4 s = __builtin_amdgcn_mfma_f32_16x16x32_bf16(
          qfrag, kfrag, (f32x4){0.f, 0.f, 0.f, 0.f}, 0, 0, 0);
#pragma unroll
      for (int r = 0; r < 4; r++) {
        float p = __expf(fminf(s[r], 80.f));
        lpart[r] += p;
        Pl[w * 16 + quad * 4 + r][ni * 16 + l16] = __float2bfloat16(p);
      }
    }
    __syncthreads();
#pragma unroll
    for (int kc = 0; kc < 2; kc++) {
      bf16x8 af[4], bfr[4];
#pragma unroll
      for (int mi = 0; mi < 4; mi++)
        af[mi] = *(const bf16x8*)(&Pl[mi * 16 + l16][kc * 32 + quad * 8]);
#pragma unroll
      for (int nj = 0; nj < 4; nj++)
        bfr[nj] = *(const bf16x8*)(&Vt[w * 64 + nj * 16 + l16][kc * 32 + quad * 8]);
#pragma unroll
      for (int mi = 0; mi < 4; mi++)
#pragma unroll
        for (int nj = 0; nj < 4; nj++)
          acc[mi][nj] = __builtin_amdgcn_mfma_f32_16x16x32_bf16(
              af[mi], bfr[nj], acc[mi][nj], 0, 0, 0);
    }
  }

#pragma unroll
  for (int r = 0; r < 4; r++) {
    float v = lpart[r];
    v += __shfl_xor(v, 1);
    v += __shfl_xor(v, 2);
    v += __shfl_xor(v, 4);
    v += __shfl_xor(v, 8);
    lpart[r] = v;
  }
  if (l16 == 0) {
#pragma unroll
    for (int r = 0; r < 4; r++) lsum[w * 16 + quad * 4 + r] = lpart[r];
  }
  __syncthreads();

  float gm = gamma[0];
#pragma unroll
  for (int mi = 0; mi < 4; mi++) {
    f32x4 lv = *(const f32x4*)&lsum[mi * 16 + quad * 4];
    float li0 = 1.f / lv[0], li1 = 1.f / lv[1], li2 = 1.f / lv[2], li3 = 1.f / lv[3];
#pragma unroll
    for (int nj = 0; nj < 4; nj++) {
      int c = w * 64 + nj * 16 + l16;
      size_t base = (((size_t)(b * 256 + c)) << 12) + q0 + mi * 16 + quad * 4;
      float4 xv = *(const float4*)(x1 + base);
      float4 o;
      o.x = gm * acc[mi][nj][0] * li0 + xv.x;
      o.y = gm * acc[mi][nj][1] * li1 + xv.y;
      o.z = gm * acc[mi][nj][2] * li2 + xv.z;
      o.w = gm * acc[mi][nj][3] * li3 + xv.w;
      *(float4*)(out + base) = o;
    }
  }
}

// ------------------------------------------------------------------- launcher
extern "C" void kernel_launch(void* const* d_in, const int* in_sizes, int n_in,
                              void* d_out, int out_size, void* d_ws, size_t ws_size,
                              hipStream_t stream) {
  const float* x1    = (const float*)d_in[0];
  const float* x2    = (const float*)d_in[1];
  const float* w1_dw = (const float*)d_in[2];
  const float* b1_dw = (const float*)d_in[3];
  const float* w1_pw = (const float*)d_in[4];
  const float* b1_pw = (const float*)d_in[5];
  const float* bn1_g = (const float*)d_in[6];
  const float* bn1_b = (const float*)d_in[7];
  const float* bn1_m = (const float*)d_in[8];
  const float* bn1_v = (const float*)d_in[9];
  const float* w2_dw = (const float*)d_in[10];
  const float* b2_dw = (const float*)d_in[11];
  const float* w2_pw = (const float*)d_in[12];
  const float* b2_pw = (const float*)d_in[13];
  const float* bn2_g = (const float*)d_in[14];
  const float* bn2_b = (const float*)d_in[15];
  const float* bn2_m = (const float*)d_in[16];
  const float* bn2_v = (const float*)d_in[17];
  const float* wq    = (const float*)d_in[18];
  const float* bq    = (const float*)d_in[19];
  const float* wk    = (const float*)d_in[20];
  const float* bk    = (const float*)d_in[21];
  const float* wv    = (const float*)d_in[22];
  const float* bv    = (const float*)d_in[23];
  const float* gamma = (const float*)d_in[24];

  float* ws  = (float*)d_ws;
  float* sub = ws;
  float* h   = ws + 4194304;
  float* x3  = ws + 12582912;
  float* x4  = ws;
  bf16* qb  = (bf16*)(ws + 4194304);
  bf16* kbf = qb + 524288;
  bf16* vvb = kbf + 524288;

  k_sub<<<16384, 256, 0, stream>>>(x1, x2, sub);

  k_dwconv<<<32768, 256, 0, stream>>>(sub, x1, w1_dw, b1_dw, h);
  k_gemm_mfma<<<dim3(64, 2, 4), 256, 0, stream>>>(h, w1_pw, b1_pw, bn1_g, bn1_b,
                                                  bn1_m, bn1_v, 1, 1, 0, x3, 512);
  k_dwconv<<<32768, 256, 0, stream>>>(sub, x2, w2_dw, b2_dw, h);
  k_gemm_mfma<<<dim3(64, 2, 4), 256, 0, stream>>>(h, w2_pw, b2_pw, bn2_g, bn2_b,
                                                  bn2_m, bn2_v, 1, 1, 0, x4, 512);

  k_gemm_qk<<<dim3(32, 2, 4), 256, 0, stream>>>(x4, x3, wq, wk, bq, bk, qb, kbf);
  k_gemm_mfma<<<dim3(64, 2, 4), 256, 0, stream>>>(x3, wv, bv, nullptr, nullptr,
                                                  nullptr, nullptr, 0, 0, 1, vvb, 256);

  k_attn_mfma<<<dim3(64, 4), 256, 0, stream>>>(qb, kbf, vvb, x1, gamma, (float*)d_out);
}